// Round 8
// baseline (144.454 us; speedup 1.0000x reference)
//
#include <hip/hip_runtime.h>

typedef _Float16 f16x8 __attribute__((ext_vector_type(8)));
typedef __fp16   fp16x2r __attribute__((ext_vector_type(2)));   // cvt_pkrtz return type
typedef float    f32x4 __attribute__((ext_vector_type(4)));

#define MFMA(a, b, c) __builtin_amdgcn_mfma_f32_16x16x32_f16((a), (b), (c), 0, 0, 0)

__device__ inline f16x8 zero8() {
    f16x8 z;
#pragma unroll
    for (int i = 0; i < 8; ++i) z[i] = (_Float16)0.0f;
    return z;
}

// layer-1 pack: rtn casts (matches R10/R13/R17 h1 numerics exactly)
__device__ inline f16x8 relu_pack8_rtn(f32x4 lo, f32x4 hi) {
    f16x8 v;
#pragma unroll
    for (int i = 0; i < 4; ++i) {
        v[i]     = (_Float16)fmaxf(lo[i], 0.f);
        v[i + 4] = (_Float16)fmaxf(hi[i], 0.f);
    }
    return v;
}

// layer-2 pack: f32 relu then cvt_pkrtz (matches R10/R13/R17 h2 numerics)
__device__ inline f16x8 relu_pack8_rtz(f32x4 lo, f32x4 hi) {
    const fp16x2r p0 = __builtin_amdgcn_cvt_pkrtz(fmaxf(lo[0], 0.f), fmaxf(lo[1], 0.f));
    const fp16x2r p1 = __builtin_amdgcn_cvt_pkrtz(fmaxf(lo[2], 0.f), fmaxf(lo[3], 0.f));
    const fp16x2r p2 = __builtin_amdgcn_cvt_pkrtz(fmaxf(hi[0], 0.f), fmaxf(hi[1], 0.f));
    const fp16x2r p3 = __builtin_amdgcn_cvt_pkrtz(fmaxf(hi[2], 0.f), fmaxf(hi[3], 0.f));
    uint4 u = { __builtin_bit_cast(unsigned int, p0), __builtin_bit_cast(unsigned int, p1),
                __builtin_bit_cast(unsigned int, p2), __builtin_bit_cast(unsigned int, p3) };
    return __builtin_bit_cast(f16x8, u);
}

// R19: R17 (best, 70.6us, VGPR 124) + F-prefetch restored, register-funded.
//   R18 post-mortem: grid is a DEAD lever (occupancy band-capped at
//   ~2 waves/SIMD for VGPR<=128, ~1 wave/SIMD above; bank conflicts scale
//   with block count -> they live in per-block prepack). Best remaining
//   lever: per-wave critical path. Largest exposed chain = tile-start F
//   global load (R17 dropped R13's prefetch to save regs).
//   Changes vs R17 (grid stays 512; quarter-pass loop shape untouched):
//     (1) R13-style F software prefetch restored (+4 long-lived regs).
//     (2) Funded by: stash {a,b,c,d} to LDS (Esc, 4KB) right after the
//         invariant block; epilogue reloads them and RECOMPUTES Rc/Rs
//         (identical ops on identical inputs -> bit-identical). Kills the
//         6 MLP-spanning live regs (a,b,c,d,Rc,Rs). Net ~ -2 arch regs.
//     (3) aLo/aHi quad-masks dropped — EXACT: B1 is zero on quad>0 lanes,
//         so all k>=8 products vanish regardless of A. Saves ~128
//         v_cndmask/tile; the ds_reads become uniform broadcasts.
//   Session laws (R10..R18):
//     - VGPR band gates waves/SIMD: <=128 -> 2/SIMD (18% occ), >128 -> 1/SIMD
//       (10% occ). Grid bumps never add residency (R16, R18).
//     - BAN: __launch_bounds__ min-waves >= 2 (5/5 miscompiles)
//     - BAN: serialized loops with LOOP-CARRIED MFMA accumulators (R14)
//     - BAN: sched_barrier in MFMA regions (R15)
//   K-slot permutation (R12-verified, both sides agree):
//     slot(s, quad, j) == channel 32*s + 16*(j>>2) + 4*quad + (j&3)
// Fragment maps: R3-hardware-verified canonical (A m=l15,k=8q+j; B k=8q+j,
// n=l15; D m=4q+r, n=l15).
__global__ __launch_bounds__(256, 1)
void DeformationCorrector_78967268704761_kernel(
        const float* __restrict__ F,
        const float* __restrict__ W1, const float* __restrict__ b1,
        const float* __restrict__ W2, const float* __restrict__ b2,
        const float* __restrict__ W3, const float* __restrict__ b3,
        float* __restrict__ out, int N)
{
    __shared__ __align__(16) _Float16 W2A[8][4][64][8]; // 32 KB  W2 A-frags (slot-permuted)
    __shared__ __align__(16) _Float16 W1A[8][16][8];    // 2 KB   W1 A-frags (k<7 -> W1, k=7 -> b1)
    __shared__ __align__(16) _Float16 W3A[4][16][8];    // 1 KB   W3 A-frags (slot-permuted, l15<4)
    __shared__ __align__(16) float    b2L[128];         // 0.5 KB b2 for C-operand init
    __shared__ __align__(16) float    b3L[4];           // 16 B   b3 for x-staging add
    __shared__ __align__(16) _Float16 invL[4][64][8];   // 4 KB   per-wave invariants; aliased as
                                                        //        x-scratch (16 B/point)
    __shared__ __align__(16) float    Esc[4][64][4];    // 4 KB   per-lane {a,b,c,d} stash
    // total ~44.5 KB: 2 blocks/CU = 89 KB <= 160 KiB (residency unchanged)

    const int tid  = threadIdx.x;
    const int lane = tid & 63;
    const int w    = tid >> 6;
    const int l15  = tid & 15;
    const int quad = (tid >> 4) & 3;

    // ---------------- weight pre-pack (once per block) ----------------
    // W2A[mt2][s][q*16+n15][j] = W2[k][n] with k = 32s + 16(j>>2) + 4q + (j&3)
    for (int m = tid; m < 128 * 128; m += 256) {
        const int k = m >> 7, n = m & 127;
        const int s = k >> 5, j = ((k >> 4) & 1) * 4 + (k & 3), q = (k >> 2) & 3;
        W2A[n >> 4][s][q * 16 + (n & 15)][j] = (_Float16)W2[m];
    }
    for (int f = tid; f < 1024; f += 256) {             // W1A[mt][l15][j] = W1[j][mt*16+l15] (j=7 -> b1)
        const int mt = f >> 7, n15 = (f >> 3) & 15, j = f & 7;
        W1A[mt][n15][j] = (_Float16)((j < 7) ? W1[j * 128 + mt * 16 + n15]
                                             : b1[mt * 16 + n15]);
    }
    for (int f = tid; f < 512; f += 256) {              // W3A[s3][q*4+c3][j] = W3[ch2][c3]
        const int s3 = f >> 7, idx = (f >> 3) & 15, j = f & 7;
        const int q = idx >> 2, c3 = idx & 3;
        const int ch2 = (2 * s3 + (j >> 2)) * 16 + q * 4 + (j & 3);
        W3A[s3][idx][j] = (_Float16)W3[ch2 * 4 + c3];
    }
    if (tid < 128) b2L[tid] = b2[tid];
    if (tid < 4)   b3L[tid] = b3[tid];
    __syncthreads();   // only barrier; all main-loop LDS traffic is wave-private or read-only

    const int ntiles = (N + 255) >> 8;
    const int stride = (int)gridDim.x;

    // prime the F prefetch for the first tile (R13-verified pattern)
    float a, b, c, d;
    {
        const int p0 = blockIdx.x * 256 + tid;
        if (blockIdx.x < ntiles && p0 < N) {
            const float4 f4 = *(const float4*)(F + 4ll * p0);
            a = f4.x; b = f4.y; c = f4.z; d = f4.w;
        } else { a = 1.f; b = 0.f; c = 0.f; d = 1.f; }
    }

    for (int tile = blockIdx.x; tile < ntiles; tile += stride) {
        // ---------------- prefetch next tile's F (overlaps whole body) ----------------
        float na = 1.f, nb = 0.f, nc = 0.f, nd = 1.f;
        {
            const int pn = (tile + stride) * 256 + tid;
            if (tile + stride < ntiles && pn < N) {
                const float4 f4 = *(const float4*)(F + 4ll * pn);
                na = f4.x; nb = f4.y; nc = f4.z; nd = f4.w;
            }
        }
        const int p = tile * 256 + tid;

        // ---------------- invariants (fp32, verified); Rc/Rs NOT kept live ----------
        {
            const float x1 = a + d, y1 = c - b, x2 = a - d, y2 = c + b;
            const float h1v = sqrtf(x1 * x1 + y1 * y1);
            const float h2v = sqrtf(x2 * x2 + y2 * y2);
            const float s1 = 0.5f * (h1v + h2v), s2 = 0.5f * (h1v - h2v);
            f16x8 iv;
            iv[0] = (_Float16)(s1 - 1.f);
            iv[1] = (_Float16)(s2 - 1.f);
            iv[2] = (_Float16)(a * a + c * c - 1.f);
            const float i3 = a * b + c * d;
            iv[3] = (_Float16)i3;
            iv[4] = (_Float16)i3;
            iv[5] = (_Float16)(b * b + d * d - 1.f);
            iv[6] = (_Float16)(a * d - b * c - 1.f);
            iv[7] = (_Float16)1.0f;
            *(f16x8*)(&invL[w][lane][0]) = iv;
        }
        // stash F for the epilogue: ends the MLP-spanning live ranges of a..d
        *(f32x4*)(&Esc[w][lane][0]) = (f32x4){a, b, c, d};

        // ---------------- four 16-point quarter-passes (R17-verified shape) --------
        // No MFMA register state is live across the loop boundary (only LDS).
#pragma unroll 1
        for (int q4 = 0; q4 < 4; ++q4) {
            // B1 frag: B[k=8q+j][n=l15] = inv_k(point q4*16+l15); quad0 only
            const f16x8 B1 = (quad == 0)
                ? *(const f16x8*)(&invL[w][q4 * 16 + l15][0]) : zero8();

            // ---- layer 1 (transposed): this quarter's B2 in registers ----
            // aLo/aHi UNMASKED (exact: B1 zero on quad>0 kills all k>=8 terms;
            // quad>0 lanes read valid W1A memory whose values are irrelevant).
            f16x8 B2[4];   // [s], 16 VGPRs
#pragma unroll
            for (int s = 0; s < 4; ++s) {
                const f16x8 aLo = *(const f16x8*)(&W1A[2 * s][l15][0]);
                const f16x8 aHi = *(const f16x8*)(&W1A[2 * s + 1][l15][0]);
                const f32x4 cz  = {0.f, 0.f, 0.f, 0.f};
                const f32x4 dLo = MFMA(aLo, B1, cz);   // ch = 32s    + 4q + r
                const f32x4 dHi = MFMA(aHi, B1, cz);   // ch = 32s+16 + 4q + r
                B2[s] = relu_pack8_rtn(dLo, dHi);
            }

            // ---- layers 2+3 fused, register-chained (fully unrolled) ----
            f32x4 acc3 = {0.f, 0.f, 0.f, 0.f};
#pragma unroll
            for (int s3 = 0; s3 < 4; ++s3) {           // mt2 pair (2*s3, 2*s3+1)
                f32x4 accE = *(const f32x4*)(&b2L[(2 * s3) * 16 + quad * 4]);
                f32x4 accO = *(const f32x4*)(&b2L[(2 * s3 + 1) * 16 + quad * 4]);
#pragma unroll
                for (int s = 0; s < 4; ++s) {
                    const f16x8 aE = *(const f16x8*)(&W2A[2 * s3][s][lane][0]);
                    const f16x8 aO = *(const f16x8*)(&W2A[2 * s3 + 1][s][lane][0]);
                    accE = MFMA(aE, B2[s], accE);
                    accO = MFMA(aO, B2[s], accO);
                }
                const f16x8 a3 = (l15 < 4) ? *(const f16x8*)(&W3A[s3][quad * 4 + l15][0]) : zero8();
                const f16x8 b3f = relu_pack8_rtz(accE, accO);
                acc3 = MFMA(a3, b3f, acc3);
            }

            // stage this quarter's x (+b3, R10-verified ordering) into invL rows
            // [16*q4, 16*q4+16). Wave-private; quarter q4+1 reads rows
            // 16*(q4+1).. (untouched iv), program order within wave -> no race.
            if (quad == 0) {
                const f32x4 b3v4 = *(const f32x4*)(&b3L[0]);
                *(f16x8*)(&invL[w][q4 * 16 + l15][0]) =
                    __builtin_bit_cast(f16x8, acc3 + b3v4);
            }
        }

        // ---------------- epilogue: reload F, recompute R, combine ----------------
        const f32x4 fv = *(const f32x4*)(&Esc[w][lane][0]);
        const float x1e = fv[0] + fv[3], y1e = fv[2] - fv[1];
        const float h1e = sqrtf(x1e * x1e + y1e * y1e);
        const float ire = 1.0f / h1e;
        const float Rc = x1e * ire, Rs = y1e * ire;     // bit-identical recompute
        const f32x4 xv = __builtin_bit_cast(f32x4, *(const f16x8*)(&invL[w][lane][0]));
        const float xm  = 0.5f * (xv[1] + xv[2]);
        const float d00 = Rc * xv[0] - Rs * xm;
        const float d01 = Rc * xm    - Rs * xv[3];
        const float d10 = Rs * xv[0] + Rc * xm;
        const float d11 = Rs * xm    + Rc * xv[3];
        if (p < N) {
            float4 o;
            o.x = fv[0] + d00; o.y = fv[1] + d01; o.z = fv[2] + d10; o.w = fv[3] + d11;
            *(float4*)(out + 4ll * p) = o;
        }

        // rotate prefetched F into place for the next tile
        a = na; b = nb; c = nc; d = nd;
    }
}

extern "C" void kernel_launch(void* const* d_in, const int* in_sizes, int n_in,
                              void* d_out, int out_size, void* d_ws, size_t ws_size,
                              hipStream_t stream) {
    const float* F  = (const float*)d_in[0];
    const float* W1 = (const float*)d_in[1];
    const float* b1 = (const float*)d_in[2];
    const float* W2 = (const float*)d_in[3];
    const float* b2 = (const float*)d_in[4];
    const float* W3 = (const float*)d_in[5];
    const float* b3 = (const float*)d_in[6];
    float* out = (float*)d_out;
    const int N = in_sizes[0] / 4;
    const int ntiles = (N + 255) / 256;
    // grid 512: R16/R18 proved larger grids only add per-block prepack cost
    // (residency is band-capped). Grid-stride keeps correctness regardless.
    const int grid = ntiles < 512 ? ntiles : 512;
    DeformationCorrector_78967268704761_kernel<<<grid, 256, 0, stream>>>(
        F, W1, b1, W2, b2, W3, b3, out, N);
}

// Round 9
// 140.085 us; speedup vs baseline: 1.0312x; 1.0312x over previous
//
#include <hip/hip_runtime.h>

typedef _Float16 f16x8 __attribute__((ext_vector_type(8)));
typedef __fp16   fp16x2r __attribute__((ext_vector_type(2)));   // cvt_pkrtz return type
typedef float    f32x4 __attribute__((ext_vector_type(4)));

#define MFMA(a, b, c) __builtin_amdgcn_mfma_f32_16x16x32_f16((a), (b), (c), 0, 0, 0)

__device__ inline f16x8 zero8() {
    f16x8 z;
#pragma unroll
    for (int i = 0; i < 8; ++i) z[i] = (_Float16)0.0f;
    return z;
}

// layer-1 pack: rtn casts (matches R10/R13/R17 h1 numerics exactly)
__device__ inline f16x8 relu_pack8_rtn(f32x4 lo, f32x4 hi) {
    f16x8 v;
#pragma unroll
    for (int i = 0; i < 4; ++i) {
        v[i]     = (_Float16)fmaxf(lo[i], 0.f);
        v[i + 4] = (_Float16)fmaxf(hi[i], 0.f);
    }
    return v;
}

// layer-2 pack: f32 relu then cvt_pkrtz (matches R10/R13/R17 h2 numerics)
__device__ inline f16x8 relu_pack8_rtz(f32x4 lo, f32x4 hi) {
    const fp16x2r p0 = __builtin_amdgcn_cvt_pkrtz(fmaxf(lo[0], 0.f), fmaxf(lo[1], 0.f));
    const fp16x2r p1 = __builtin_amdgcn_cvt_pkrtz(fmaxf(lo[2], 0.f), fmaxf(lo[3], 0.f));
    const fp16x2r p2 = __builtin_amdgcn_cvt_pkrtz(fmaxf(hi[0], 0.f), fmaxf(hi[1], 0.f));
    const fp16x2r p3 = __builtin_amdgcn_cvt_pkrtz(fmaxf(hi[2], 0.f), fmaxf(hi[3], 0.f));
    uint4 u = { __builtin_bit_cast(unsigned int, p0), __builtin_bit_cast(unsigned int, p1),
                __builtin_bit_cast(unsigned int, p2), __builtin_bit_cast(unsigned int, p3) };
    return __builtin_bit_cast(f16x8, u);
}

// R20: R17 core (best, 70.6us, VGPR 124) + PIPELINED PREPACK + R19's exact
//   unmask. Main loop and epilogue are R17 byte-for-byte except aLo/aHi masks.
//   R18/R19 post-mortem chain:
//     - R18 (R17 + grid 1024, same occupancy): +11us => one extra GENERATION
//       of block prologues costs ~11us. Same signal R13->R16 (+0.5 gen =
//       +4.5us). The prologue cost is the W2A prepack: 64 SERIAL scalar
//       global loads per thread (load->cvt->ds_write chain, ~300-500cy each,
//       unpipelined) ~ 10us — 14% of the dispatch before any MFMA issues.
//     - R19 (prefetch + LDS stash): VGPR 132 > 128 -> 1-wave band, 86us.
//       The <=128 budget cannot fund the F prefetch. Reverted.
//   Changes vs R17:
//     (1) W2 prepack float4-vectorized (16 loads/thread, was 64 scalar) and
//         explicitly batched 4-in-flight. Transient ~16 VGPRs, prepack-local
//         (below main-loop pressure -> VGPR_Count unchanged). Mapping:
//         m4 in [0,4096), k=m4>>5, n0=4*(m4&31); k constant over the 4 elems
//         (n0+3<=127) -> identical (k,n)->W2A scatter as R17.
//     (2) W1A/W3A/b2L/b3L loads hoisted into independent batches issued
//         before the W2A loop (overlap its latency); writes after.
//     (3) aLo/aHi quad-masks dropped — EXACT (R19-verified, absmax 0.0078):
//         B1 is zero on quad>0 lanes, so all k>=8 products vanish.
//   Session laws (R10..R19):
//     - VGPR band gates waves/SIMD: <=128 -> 2/SIMD (18% occ), >128 -> 1/SIMD
//       (10% occ). Grid bumps never add residency (R16, R18).
//     - BAN: __launch_bounds__ min-waves >= 2 (5/5 miscompiles)
//     - BAN: serialized loops with LOOP-CARRIED MFMA accumulators (R14)
//     - BAN: sched_barrier in MFMA regions (R15)
//   K-slot permutation (R12-verified, both sides agree):
//     slot(s, quad, j) == channel 32*s + 16*(j>>2) + 4*quad + (j&3)
// Fragment maps: R3-hardware-verified canonical (A m=l15,k=8q+j; B k=8q+j,
// n=l15; D m=4q+r, n=l15).
__global__ __launch_bounds__(256, 1)
void DeformationCorrector_78967268704761_kernel(
        const float* __restrict__ F,
        const float* __restrict__ W1, const float* __restrict__ b1,
        const float* __restrict__ W2, const float* __restrict__ b2,
        const float* __restrict__ W3, const float* __restrict__ b3,
        float* __restrict__ out, int N)
{
    __shared__ __align__(16) _Float16 W2A[8][4][64][8]; // 32 KB  W2 A-frags (slot-permuted)
    __shared__ __align__(16) _Float16 W1A[8][16][8];    // 2 KB   W1 A-frags (k<7 -> W1, k=7 -> b1)
    __shared__ __align__(16) _Float16 W3A[4][16][8];    // 1 KB   W3 A-frags (slot-permuted, l15<4)
    __shared__ __align__(16) float    b2L[128];         // 0.5 KB b2 for C-operand init
    __shared__ __align__(16) float    b3L[4];           // 16 B   b3 for x-staging add
    __shared__ __align__(16) _Float16 invL[4][64][8];   // 4 KB   per-wave invariants; aliased as
                                                        //        x-scratch (16 B/point)

    const int tid  = threadIdx.x;
    const int lane = tid & 63;
    const int w    = tid >> 6;
    const int l15  = tid & 15;
    const int quad = (tid >> 4) & 3;

    // ---------------- weight pre-pack (once per block, PIPELINED) ----------------
    // (2) hoist the small-table loads first, as independent batches:
    float w1v[4];
    {
        const int mt = tid >> 7, n15 = (tid >> 3) & 15, j = tid & 7;   // f = tid + it*256
#pragma unroll
        for (int it = 0; it < 4; ++it) {
            const int mtt = (tid + it * 256) >> 7;                     // only mt varies with it
            w1v[it] = (j < 7) ? W1[j * 128 + mtt * 16 + n15] : b1[mtt * 16 + n15];
        }
        (void)mt;
    }
    float w3v[2];
    {
#pragma unroll
        for (int it = 0; it < 2; ++it) {
            const int f = tid + it * 256;
            const int s3 = f >> 7, idx = (f >> 3) & 15, j = f & 7;
            const int q = idx >> 2, c3 = idx & 3;
            const int ch2 = (2 * s3 + (j >> 2)) * 16 + q * 4 + (j & 3);
            w3v[it] = W3[ch2 * 4 + c3];
        }
    }
    const float b2v = (tid < 128) ? b2[tid] : 0.f;
    const float b3v = (tid < 4)   ? b3[tid] : 0.f;

    // (1) W2A: float4 loads, 4 in flight per batch; same scatter as R17.
    // W2A[n>>4][s][q*16+(n&15)][j] = W2[k][n], k = 32s + 16(j>>2) + 4q + (j&3)
#pragma unroll
    for (int i4 = 0; i4 < 4; ++i4) {
        f32x4 v[4];
#pragma unroll
        for (int u = 0; u < 4; ++u)
            v[u] = *(const f32x4*)(W2 + 4ll * (tid + (i4 * 4 + u) * 256));
#pragma unroll
        for (int u = 0; u < 4; ++u) {
            const int m4 = tid + (i4 * 4 + u) * 256;     // float4 index in W2
            const int k  = m4 >> 5;                      // = (4*m4) >> 7
            const int n0 = (m4 & 31) * 4;                // = (4*m4) & 127 (k const over e)
            const int s = k >> 5, j = ((k >> 4) & 1) * 4 + (k & 3), q = (k >> 2) & 3;
#pragma unroll
            for (int e = 0; e < 4; ++e) {
                const int n = n0 + e;
                W2A[n >> 4][s][q * 16 + (n & 15)][j] = (_Float16)v[u][e];
            }
        }
    }
    // writes for the hoisted batches:
    {
        const int n15 = (tid >> 3) & 15, j = tid & 7;
#pragma unroll
        for (int it = 0; it < 4; ++it) {
            const int mtt = (tid + it * 256) >> 7;
            W1A[mtt][n15][j] = (_Float16)w1v[it];
        }
    }
    {
#pragma unroll
        for (int it = 0; it < 2; ++it) {
            const int f = tid + it * 256;
            const int s3 = f >> 7, idx = (f >> 3) & 15;
            W3A[s3][idx][f & 7] = (_Float16)w3v[it];
        }
    }
    if (tid < 128) b2L[tid] = b2v;
    if (tid < 4)   b3L[tid] = b3v;
    __syncthreads();   // only barrier; all main-loop LDS traffic is wave-private or read-only

    const int ntiles = (N + 255) >> 8;
    const int stride = (int)gridDim.x;

    for (int tile = blockIdx.x; tile < ntiles; tile += stride) {
        const int p = tile * 256 + tid;

        // ---------------- F load (no SW prefetch; TLP covers latency) ----------
        float a, b, c, d;
        if (p < N) {
            const float4 f4 = *(const float4*)(F + 4ll * p);
            a = f4.x; b = f4.y; c = f4.z; d = f4.w;
        } else { a = 1.f; b = 0.f; c = 0.f; d = 1.f; }

        // ---------------- invariants + polar (fp32, verified) ----------------
        const float x1 = a + d, y1 = c - b, x2 = a - d, y2 = c + b;
        const float h1v = sqrtf(x1 * x1 + y1 * y1);
        const float h2v = sqrtf(x2 * x2 + y2 * y2);
        const float s1 = 0.5f * (h1v + h2v), s2 = 0.5f * (h1v - h2v);
        const float ir = 1.0f / h1v;
        const float Rc = x1 * ir, Rs = y1 * ir;
        f16x8 iv;
        iv[0] = (_Float16)(s1 - 1.f);
        iv[1] = (_Float16)(s2 - 1.f);
        iv[2] = (_Float16)(a * a + c * c - 1.f);
        const float i3 = a * b + c * d;
        iv[3] = (_Float16)i3;
        iv[4] = (_Float16)i3;
        iv[5] = (_Float16)(b * b + d * d - 1.f);
        iv[6] = (_Float16)(a * d - b * c - 1.f);
        iv[7] = (_Float16)1.0f;
        *(f16x8*)(&invL[w][lane][0]) = iv;

        // ---------------- four 16-point quarter-passes (R17-verified shape) --------
        // No MFMA register state is live across the loop boundary (only LDS).
#pragma unroll 1
        for (int q4 = 0; q4 < 4; ++q4) {
            // B1 frag: B[k=8q+j][n=l15] = inv_k(point q4*16+l15); quad0 only
            const f16x8 B1 = (quad == 0)
                ? *(const f16x8*)(&invL[w][q4 * 16 + l15][0]) : zero8();

            // ---- layer 1 (transposed): this quarter's B2 in registers ----
            // aLo/aHi UNMASKED (exact, R19-verified: B1 zero on quad>0 kills
            // all k>=8 terms regardless of A).
            f16x8 B2[4];   // [s], 16 VGPRs
#pragma unroll
            for (int s = 0; s < 4; ++s) {
                const f16x8 aLo = *(const f16x8*)(&W1A[2 * s][l15][0]);
                const f16x8 aHi = *(const f16x8*)(&W1A[2 * s + 1][l15][0]);
                const f32x4 cz  = {0.f, 0.f, 0.f, 0.f};
                const f32x4 dLo = MFMA(aLo, B1, cz);   // ch = 32s    + 4q + r
                const f32x4 dHi = MFMA(aHi, B1, cz);   // ch = 32s+16 + 4q + r
                B2[s] = relu_pack8_rtn(dLo, dHi);
            }

            // ---- layers 2+3 fused, register-chained (fully unrolled) ----
            f32x4 acc3 = {0.f, 0.f, 0.f, 0.f};
#pragma unroll
            for (int s3 = 0; s3 < 4; ++s3) {           // mt2 pair (2*s3, 2*s3+1)
                f32x4 accE = *(const f32x4*)(&b2L[(2 * s3) * 16 + quad * 4]);
                f32x4 accO = *(const f32x4*)(&b2L[(2 * s3 + 1) * 16 + quad * 4]);
#pragma unroll
                for (int s = 0; s < 4; ++s) {
                    const f16x8 aE = *(const f16x8*)(&W2A[2 * s3][s][lane][0]);
                    const f16x8 aO = *(const f16x8*)(&W2A[2 * s3 + 1][s][lane][0]);
                    accE = MFMA(aE, B2[s], accE);
                    accO = MFMA(aO, B2[s], accO);
                }
                const f16x8 a3 = (l15 < 4) ? *(const f16x8*)(&W3A[s3][quad * 4 + l15][0]) : zero8();
                const f16x8 b3f = relu_pack8_rtz(accE, accO);
                acc3 = MFMA(a3, b3f, acc3);
            }

            // stage this quarter's x (+b3, R10-verified ordering) into invL rows
            // [16*q4, 16*q4+16). Wave-private; quarter q4+1 reads rows
            // 16*(q4+1).. (untouched iv), program order within wave -> no race.
            if (quad == 0) {
                const f32x4 b3v4 = *(const f32x4*)(&b3L[0]);
                *(f16x8*)(&invL[w][q4 * 16 + l15][0]) =
                    __builtin_bit_cast(f16x8, acc3 + b3v4);
            }
        }

        // ---------------- epilogue: x via invL alias -> R@x + F ----------------
        const f32x4 xv = __builtin_bit_cast(f32x4, *(const f16x8*)(&invL[w][lane][0]));
        const float xm  = 0.5f * (xv[1] + xv[2]);
        const float d00 = Rc * xv[0] - Rs * xm;
        const float d01 = Rc * xm    - Rs * xv[3];
        const float d10 = Rs * xv[0] + Rc * xm;
        const float d11 = Rs * xm    + Rc * xv[3];
        if (p < N) {
            float4 o;
            o.x = a + d00; o.y = b + d01; o.z = c + d10; o.w = d + d11;
            *(float4*)(out + 4ll * p) = o;
        }
    }
}

extern "C" void kernel_launch(void* const* d_in, const int* in_sizes, int n_in,
                              void* d_out, int out_size, void* d_ws, size_t ws_size,
                              hipStream_t stream) {
    const float* F  = (const float*)d_in[0];
    const float* W1 = (const float*)d_in[1];
    const float* b1 = (const float*)d_in[2];
    const float* W2 = (const float*)d_in[3];
    const float* b2 = (const float*)d_in[4];
    const float* W3 = (const float*)d_in[5];
    const float* b3 = (const float*)d_in[6];
    float* out = (float*)d_out;
    const int N = in_sizes[0] / 4;
    const int ntiles = (N + 255) / 256;
    // grid 512: one generation of block prologues (R16/R18 proved extra
    // generations cost ~10us each). Grid-stride keeps correctness regardless.
    const int grid = ntiles < 512 ? ntiles : 512;
    DeformationCorrector_78967268704761_kernel<<<grid, 256, 0, stream>>>(
        F, W1, b1, W2, b2, W3, b3, out, N);
}

// Round 10
// 136.104 us; speedup vs baseline: 1.0614x; 1.0293x over previous
//
#include <hip/hip_runtime.h>

typedef _Float16 f16x8 __attribute__((ext_vector_type(8)));
typedef __fp16   fp16x2r __attribute__((ext_vector_type(2)));   // cvt_pkrtz return type
typedef float    f32x4 __attribute__((ext_vector_type(4)));

#define MFMA(a, b, c) __builtin_amdgcn_mfma_f32_16x16x32_f16((a), (b), (c), 0, 0, 0)

__device__ inline f16x8 zero8() {
    f16x8 z;
#pragma unroll
    for (int i = 0; i < 8; ++i) z[i] = (_Float16)0.0f;
    return z;
}

// layer-1 pack: rtn casts (matches R10/R13/R17 h1 numerics exactly)
__device__ inline f16x8 relu_pack8_rtn(f32x4 lo, f32x4 hi) {
    f16x8 v;
#pragma unroll
    for (int i = 0; i < 4; ++i) {
        v[i]     = (_Float16)fmaxf(lo[i], 0.f);
        v[i + 4] = (_Float16)fmaxf(hi[i], 0.f);
    }
    return v;
}

// layer-2 pack: f32 relu then cvt_pkrtz (matches R10/R13/R17 h2 numerics)
__device__ inline f16x8 relu_pack8_rtz(f32x4 lo, f32x4 hi) {
    const fp16x2r p0 = __builtin_amdgcn_cvt_pkrtz(fmaxf(lo[0], 0.f), fmaxf(lo[1], 0.f));
    const fp16x2r p1 = __builtin_amdgcn_cvt_pkrtz(fmaxf(lo[2], 0.f), fmaxf(lo[3], 0.f));
    const fp16x2r p2 = __builtin_amdgcn_cvt_pkrtz(fmaxf(hi[0], 0.f), fmaxf(hi[1], 0.f));
    const fp16x2r p3 = __builtin_amdgcn_cvt_pkrtz(fmaxf(hi[2], 0.f), fmaxf(hi[3], 0.f));
    uint4 u = { __builtin_bit_cast(unsigned int, p0), __builtin_bit_cast(unsigned int, p1),
                __builtin_bit_cast(unsigned int, p2), __builtin_bit_cast(unsigned int, p3) };
    return __builtin_bit_cast(f16x8, u);
}

// R21: R17 core (best, 70.6us, VGPR 124) + LOAD-ONLY prepack pipelining.
//   R20 post-mortem (77us): two self-inflicted hits —
//     (a) VGPR_Count 132 > 128: prologue transients (4x f32x4 + hoisted
//         small tables live together) set the KERNEL-WIDE register peak.
//         Law: VGPR allocation is static over the whole kernel; prologue
//         pressure counts against the main loop's occupancy band.
//     (b) bank conflicts 786K -> 3.93M: float4-scatter writes put 16 lanes
//         on one bank (scalar b16 stores at 16B lane-stride).
//   R21 fix: keep R17's EXACT scalar write pattern (~4-way, 786K baseline),
//   batch only the LOADS 8-in-flight (t[8] scalars -> drain -> 8 cvt+write,
//   x8 batches). Serial chain 64x~400cy (~10.6us, = the R17->R18
//   per-generation delta) -> 8x~450cy (~1.5us). Transient cost: 8 VGPRs,
//   dead before the main loop. W1A (4 loads) / W3A (2 loads) same treatment.
//   Main loop/epilogue: R17 verbatim + R19/R20's twice-verified exact
//   unmask of aLo/aHi (B1 rows k>=8 are zero, A there is don't-care).
//   Session laws (R10..R20):
//     - VGPR band gates waves/SIMD: <=128 -> 2/SIMD (18% occ), >128 ->
//       1/SIMD (10% occ). Peak includes prologue (R20).
//     - grid is a dead lever; extra block generations cost ~10us prologue
//       each (R16, R18). Grid stays 512.
//     - BAN: __launch_bounds__ min-waves >= 2 (5/5 miscompiles)
//     - BAN: serialized loops with LOOP-CARRIED MFMA accumulators (R14)
//     - BAN: sched_barrier in MFMA regions (R15)
//   K-slot permutation (R12-verified, both sides agree):
//     slot(s, quad, j) == channel 32*s + 16*(j>>2) + 4*quad + (j&3)
// Fragment maps: R3-hardware-verified canonical (A m=l15,k=8q+j; B k=8q+j,
// n=l15; D m=4q+r, n=l15).
__global__ __launch_bounds__(256, 1)
void DeformationCorrector_78967268704761_kernel(
        const float* __restrict__ F,
        const float* __restrict__ W1, const float* __restrict__ b1,
        const float* __restrict__ W2, const float* __restrict__ b2,
        const float* __restrict__ W3, const float* __restrict__ b3,
        float* __restrict__ out, int N)
{
    __shared__ __align__(16) _Float16 W2A[8][4][64][8]; // 32 KB  W2 A-frags (slot-permuted)
    __shared__ __align__(16) _Float16 W1A[8][16][8];    // 2 KB   W1 A-frags (k<7 -> W1, k=7 -> b1)
    __shared__ __align__(16) _Float16 W3A[4][16][8];    // 1 KB   W3 A-frags (slot-permuted, l15<4)
    __shared__ __align__(16) float    b2L[128];         // 0.5 KB b2 for C-operand init
    __shared__ __align__(16) float    b3L[4];           // 16 B   b3 for x-staging add
    __shared__ __align__(16) _Float16 invL[4][64][8];   // 4 KB   per-wave invariants; aliased as
                                                        //        x-scratch (16 B/point)

    const int tid  = threadIdx.x;
    const int lane = tid & 63;
    const int w    = tid >> 6;
    const int l15  = tid & 15;
    const int quad = (tid >> 4) & 3;

    // ---------------- weight pre-pack (once per block; loads batched) ------------
    // W2A: 8 batches of 8 scalar loads in flight; write pattern = R17 verbatim.
    // W2A[n>>4][s][q*16+(n&15)][j] = W2[k][n], k = 32s + 16(j>>2) + 4q + (j&3)
#pragma unroll
    for (int b8 = 0; b8 < 8; ++b8) {
        float t[8];
#pragma unroll
        for (int u = 0; u < 8; ++u)
            t[u] = W2[tid + (b8 * 8 + u) * 256];
#pragma unroll
        for (int u = 0; u < 8; ++u) {
            const int m = tid + (b8 * 8 + u) * 256;
            const int k = m >> 7, n = m & 127;
            const int s = k >> 5, j = ((k >> 4) & 1) * 4 + (k & 3), q = (k >> 2) & 3;
            W2A[n >> 4][s][q * 16 + (n & 15)][j] = (_Float16)t[u];
        }
    }
    {   // W1A: 4 loads batched.  W1A[mt][n15][j] = W1[j][mt*16+n15] (j=7 -> b1)
        float t[4];
        const int n15 = (tid >> 3) & 15, j = tid & 7;
#pragma unroll
        for (int it = 0; it < 4; ++it) {
            const int mt = (tid + it * 256) >> 7;
            t[it] = (j < 7) ? W1[j * 128 + mt * 16 + n15] : b1[mt * 16 + n15];
        }
#pragma unroll
        for (int it = 0; it < 4; ++it) {
            const int mt = (tid + it * 256) >> 7;
            W1A[mt][n15][j] = (_Float16)t[it];
        }
    }
    {   // W3A: 2 loads batched.  W3A[s3][q*4+c3][j] = W3[ch2][c3]
        float t[2];
#pragma unroll
        for (int it = 0; it < 2; ++it) {
            const int f = tid + it * 256;
            const int s3 = f >> 7, idx = (f >> 3) & 15, j = f & 7;
            const int q = idx >> 2, c3 = idx & 3;
            const int ch2 = (2 * s3 + (j >> 2)) * 16 + q * 4 + (j & 3);
            t[it] = W3[ch2 * 4 + c3];
        }
#pragma unroll
        for (int it = 0; it < 2; ++it) {
            const int f = tid + it * 256;
            W3A[f >> 7][(f >> 3) & 15][f & 7] = (_Float16)t[it];
        }
    }
    if (tid < 128) b2L[tid] = b2[tid];
    if (tid < 4)   b3L[tid] = b3[tid];
    __syncthreads();   // only barrier; all main-loop LDS traffic is wave-private or read-only

    const int ntiles = (N + 255) >> 8;
    const int stride = (int)gridDim.x;

    for (int tile = blockIdx.x; tile < ntiles; tile += stride) {
        const int p = tile * 256 + tid;

        // ---------------- F load (no SW prefetch; TLP covers latency) ----------
        float a, b, c, d;
        if (p < N) {
            const float4 f4 = *(const float4*)(F + 4ll * p);
            a = f4.x; b = f4.y; c = f4.z; d = f4.w;
        } else { a = 1.f; b = 0.f; c = 0.f; d = 1.f; }

        // ---------------- invariants + polar (fp32, verified) ----------------
        const float x1 = a + d, y1 = c - b, x2 = a - d, y2 = c + b;
        const float h1v = sqrtf(x1 * x1 + y1 * y1);
        const float h2v = sqrtf(x2 * x2 + y2 * y2);
        const float s1 = 0.5f * (h1v + h2v), s2 = 0.5f * (h1v - h2v);
        const float ir = 1.0f / h1v;
        const float Rc = x1 * ir, Rs = y1 * ir;
        f16x8 iv;
        iv[0] = (_Float16)(s1 - 1.f);
        iv[1] = (_Float16)(s2 - 1.f);
        iv[2] = (_Float16)(a * a + c * c - 1.f);
        const float i3 = a * b + c * d;
        iv[3] = (_Float16)i3;
        iv[4] = (_Float16)i3;
        iv[5] = (_Float16)(b * b + d * d - 1.f);
        iv[6] = (_Float16)(a * d - b * c - 1.f);
        iv[7] = (_Float16)1.0f;
        *(f16x8*)(&invL[w][lane][0]) = iv;

        // ---------------- four 16-point quarter-passes (R17-verified shape) --------
        // No MFMA register state is live across the loop boundary (only LDS).
#pragma unroll 1
        for (int q4 = 0; q4 < 4; ++q4) {
            // B1 frag: B[k=8q+j][n=l15] = inv_k(point q4*16+l15); quad0 only
            const f16x8 B1 = (quad == 0)
                ? *(const f16x8*)(&invL[w][q4 * 16 + l15][0]) : zero8();

            // ---- layer 1 (transposed): this quarter's B2 in registers ----
            // aLo/aHi UNMASKED (exact, R19/R20-verified: B1 zero on quad>0
            // kills all k>=8 terms regardless of A).
            f16x8 B2[4];   // [s], 16 VGPRs
#pragma unroll
            for (int s = 0; s < 4; ++s) {
                const f16x8 aLo = *(const f16x8*)(&W1A[2 * s][l15][0]);
                const f16x8 aHi = *(const f16x8*)(&W1A[2 * s + 1][l15][0]);
                const f32x4 cz  = {0.f, 0.f, 0.f, 0.f};
                const f32x4 dLo = MFMA(aLo, B1, cz);   // ch = 32s    + 4q + r
                const f32x4 dHi = MFMA(aHi, B1, cz);   // ch = 32s+16 + 4q + r
                B2[s] = relu_pack8_rtn(dLo, dHi);
            }

            // ---- layers 2+3 fused, register-chained (fully unrolled) ----
            f32x4 acc3 = {0.f, 0.f, 0.f, 0.f};
#pragma unroll
            for (int s3 = 0; s3 < 4; ++s3) {           // mt2 pair (2*s3, 2*s3+1)
                f32x4 accE = *(const f32x4*)(&b2L[(2 * s3) * 16 + quad * 4]);
                f32x4 accO = *(const f32x4*)(&b2L[(2 * s3 + 1) * 16 + quad * 4]);
#pragma unroll
                for (int s = 0; s < 4; ++s) {
                    const f16x8 aE = *(const f16x8*)(&W2A[2 * s3][s][lane][0]);
                    const f16x8 aO = *(const f16x8*)(&W2A[2 * s3 + 1][s][lane][0]);
                    accE = MFMA(aE, B2[s], accE);
                    accO = MFMA(aO, B2[s], accO);
                }
                const f16x8 a3 = (l15 < 4) ? *(const f16x8*)(&W3A[s3][quad * 4 + l15][0]) : zero8();
                const f16x8 b3f = relu_pack8_rtz(accE, accO);
                acc3 = MFMA(a3, b3f, acc3);
            }

            // stage this quarter's x (+b3, R10-verified ordering) into invL rows
            // [16*q4, 16*q4+16). Wave-private; quarter q4+1 reads rows
            // 16*(q4+1).. (untouched iv), program order within wave -> no race.
            if (quad == 0) {
                const f32x4 b3v4 = *(const f32x4*)(&b3L[0]);
                *(f16x8*)(&invL[w][q4 * 16 + l15][0]) =
                    __builtin_bit_cast(f16x8, acc3 + b3v4);
            }
        }

        // ---------------- epilogue: x via invL alias -> R@x + F ----------------
        const f32x4 xv = __builtin_bit_cast(f32x4, *(const f16x8*)(&invL[w][lane][0]));
        const float xm  = 0.5f * (xv[1] + xv[2]);
        const float d00 = Rc * xv[0] - Rs * xm;
        const float d01 = Rc * xm    - Rs * xv[3];
        const float d10 = Rs * xv[0] + Rc * xm;
        const float d11 = Rs * xm    + Rc * xv[3];
        if (p < N) {
            float4 o;
            o.x = a + d00; o.y = b + d01; o.z = c + d10; o.w = d + d11;
            *(float4*)(out + 4ll * p) = o;
        }
    }
}

extern "C" void kernel_launch(void* const* d_in, const int* in_sizes, int n_in,
                              void* d_out, int out_size, void* d_ws, size_t ws_size,
                              hipStream_t stream) {
    const float* F  = (const float*)d_in[0];
    const float* W1 = (const float*)d_in[1];
    const float* b1 = (const float*)d_in[2];
    const float* W2 = (const float*)d_in[3];
    const float* b2 = (const float*)d_in[4];
    const float* W3 = (const float*)d_in[5];
    const float* b3 = (const float*)d_in[6];
    float* out = (float*)d_out;
    const int N = in_sizes[0] / 4;
    const int ntiles = (N + 255) / 256;
    // grid 512: one generation of block prologues (R16/R18: extra generations
    // cost ~10us each). Grid-stride keeps correctness regardless.
    const int grid = ntiles < 512 ? ntiles : 512;
    DeformationCorrector_78967268704761_kernel<<<grid, 256, 0, stream>>>(
        F, W1, b1, W2, b2, W3, b3, out, N);
}